// Round 1
// baseline (993.735 us; speedup 1.0000x reference)
//
#include <hip/hip_runtime.h>
#include <hip/hip_bf16.h>
#include <cstdint>
#include <cstddef>

// Problem constants
#define B_   2
#define T_   2048
#define DIM_ 4096
#define H_   32
#define HKV_ 8
#define DH_  128
// M dimension of all GEMMs
#define MROWS (B_*T_)   // 4096

typedef __bf16 bf16_t;
typedef bf16_t bf16x8 __attribute__((ext_vector_type(8)));
typedef bf16_t bf16x4 __attribute__((ext_vector_type(4)));
typedef float  f32x4  __attribute__((ext_vector_type(4)));

typedef __attribute__((address_space(1))) void gvoid_t;
typedef __attribute__((address_space(3))) void lvoid_t;

__device__ __forceinline__ void gld_lds16(const void* g, void* l) {
  // async global->LDS, 16B per lane; LDS dest is wave-uniform base + lane*16
  __builtin_amdgcn_global_load_lds((gvoid_t*)g, (lvoid_t*)l, 16, 0, 0);
}

__device__ __forceinline__ f32x4 mfma16(bf16x8 a, bf16x8 b, f32x4 c) {
  return __builtin_amdgcn_mfma_f32_16x16x32_bf16(a, b, c, 0, 0, 0);
}

// ---------------------------------------------------------------------------
// 1) elementwise cast fp32 -> bf16 (X)
// ---------------------------------------------------------------------------
__global__ void cast_f32_bf16(const float* __restrict__ in,
                              bf16_t* __restrict__ out, int n4) {
  int i = blockIdx.x * blockDim.x + threadIdx.x;
  if (i < n4) {
    float4 v = ((const float4*)in)[i];
    bf16x4 o;
    o[0] = (bf16_t)v.x; o[1] = (bf16_t)v.y; o[2] = (bf16_t)v.z; o[3] = (bf16_t)v.w;
    ((bf16x4*)out)[i] = o;
  }
}

// ---------------------------------------------------------------------------
// 2) transpose + cast: in fp32 [K][N] -> out bf16 [N][K]
// ---------------------------------------------------------------------------
__global__ void transpose_cast(const float* __restrict__ in,
                               bf16_t* __restrict__ out, int K, int N) {
  __shared__ float tile[32][33];
  int n0 = blockIdx.x * 32, k0 = blockIdx.y * 32;
  int tx = threadIdx.x, ty = threadIdx.y;
#pragma unroll
  for (int j = 0; j < 4; ++j)
    tile[ty + j*8][tx] = in[(size_t)(k0 + ty + j*8) * N + n0 + tx];
  __syncthreads();
#pragma unroll
  for (int j = 0; j < 4; ++j)
    out[(size_t)(n0 + ty + j*8) * K + k0 + tx] = (bf16_t)tile[tx][ty + j*8];
}

// ---------------------------------------------------------------------------
// 3) bf16 MFMA GEMM, m97 structure: C[M][N] = A[M][K] * BT[N][K]^T
//    128x128 tile, BK=32, 256 threads (2x2 waves, 4x4 16x16 frags each)
// ---------------------------------------------------------------------------
template <int OUT_F32>
__global__ __launch_bounds__(256, 2)
void gemm_bt(const bf16_t* __restrict__ A, const bf16_t* __restrict__ BT,
             void* __restrict__ C, int M, int N, int K) {
  __shared__ __align__(16) bf16_t Als[128 * 32];
  __shared__ __align__(16) bf16_t Bls[128 * 32];
  const int tid  = threadIdx.x;
  const int wave = tid >> 6, lane = tid & 63;
  const int quad = lane >> 4, l16 = lane & 15;
  const int wm = wave >> 1, wn = wave & 1;
  const int m0 = blockIdx.y * 128, n0 = blockIdx.x * 128;

  f32x4 acc[4][4] = {};

  const int srow = lane >> 2;        // 0..15 within 1KB chunk (16 rows x 64B)
  const int scol = (lane & 3) * 8;   // element offset

  for (int k0 = 0; k0 < K; k0 += 32) {
    // stage A tile [128][32] : 8 chunks of 1KB, 2 per wave
#pragma unroll
    for (int c = 0; c < 2; ++c) {
      int ch = wave * 2 + c;
      gld_lds16(A + (size_t)(m0 + ch*16 + srow) * K + k0 + scol,
                &Als[ch*512 + srow*32 + scol]);
    }
    // stage BT tile [128][32]
#pragma unroll
    for (int c = 0; c < 2; ++c) {
      int ch = wave * 2 + c;
      gld_lds16(BT + (size_t)(n0 + ch*16 + srow) * K + k0 + scol,
                &Bls[ch*512 + srow*32 + scol]);
    }
    __syncthreads();

    bf16x8 af[4], bfr[4];
#pragma unroll
    for (int mi = 0; mi < 4; ++mi)
      af[mi] = *(const bf16x8*)&Als[(wm*64 + mi*16 + l16)*32 + quad*8];
#pragma unroll
    for (int ni = 0; ni < 4; ++ni)
      bfr[ni] = *(const bf16x8*)&Bls[(wn*64 + ni*16 + l16)*32 + quad*8];
#pragma unroll
    for (int mi = 0; mi < 4; ++mi)
#pragma unroll
      for (int ni = 0; ni < 4; ++ni)
        acc[mi][ni] = mfma16(af[mi], bfr[ni], acc[mi][ni]);
    __syncthreads();
  }

  // epilogue: C/D layout col = lane&15, row = quad*4 + r
#pragma unroll
  for (int mi = 0; mi < 4; ++mi)
#pragma unroll
    for (int ni = 0; ni < 4; ++ni)
#pragma unroll
      for (int r = 0; r < 4; ++r) {
        int row = m0 + wm*64 + mi*16 + quad*4 + r;
        int col = n0 + wn*64 + ni*16 + l16;
        if (OUT_F32)
          ((float*)C)[(size_t)row * N + col] = acc[mi][ni][r];
        else
          ((bf16_t*)C)[(size_t)row * N + col] = (bf16_t)acc[mi][ni][r];
      }
}

// ---------------------------------------------------------------------------
// 4) in-place RoPE on bf16 [B,T,Hn,128]; pairs (d, d+64), pos = t
// ---------------------------------------------------------------------------
__global__ void rope_kernel(bf16_t* __restrict__ X, int Hn, int total) {
  int i = blockIdx.x * blockDim.x + threadIdx.x;
  if (i >= total) return;
  int d   = i & 63;
  int rem = i >> 6;
  int h   = rem % Hn; rem /= Hn;
  int t   = rem % T_;
  int b   = rem / T_;
  size_t base = ((size_t)(b * T_ + t) * Hn + h) * DH_;
  float x1 = (float)X[base + d];
  float x2 = (float)X[base + 64 + d];
  // inv_freq = theta^(-d/64) = exp(-d * ln(10000)/64)
  float inv_freq = expf(-(float)d * 0.14391156758f);
  float ang = (float)t * inv_freq;
  float s, c;
  sincosf(ang, &s, &c);
  X[base + d]      = (bf16_t)(x1 * c - x2 * s);
  X[base + 64 + d] = (bf16_t)(x1 * s + x2 * c);
}

// ---------------------------------------------------------------------------
// 5) V transpose: Vb [b][t][kv][128] -> VT [b][kv][128][T]
// ---------------------------------------------------------------------------
__global__ void v_transpose(const bf16_t* __restrict__ Vb,
                            bf16_t* __restrict__ VT) {
  __shared__ bf16_t tile[32][33];
  int t0 = blockIdx.x * 32;   // T
  int d0 = blockIdx.y * 32;   // dh
  int bk = blockIdx.z;        // b*8+kv
  int b = bk >> 3, kv = bk & 7;
  int tx = threadIdx.x, ty = threadIdx.y;
#pragma unroll
  for (int j = 0; j < 4; ++j)
    tile[ty + j*8][tx] =
        Vb[(size_t)(b * T_ + t0 + ty + j*8) * (HKV_*DH_) + kv*DH_ + d0 + tx];
  __syncthreads();
#pragma unroll
  for (int j = 0; j < 4; ++j)
    VT[((size_t)bk * DH_ + d0 + ty + j*8) * T_ + t0 + tx] = tile[tx][ty + j*8];
}

// ---------------------------------------------------------------------------
// 6) causal flash attention, BQ=128, BKV=64, 256 threads
//    grid (T/128, H, B). kv head = h>>2 (G=4).
// ---------------------------------------------------------------------------
__global__ __launch_bounds__(256, 2)
void flash_attn(const bf16_t* __restrict__ Qb, const bf16_t* __restrict__ Kb,
                const bf16_t* __restrict__ VT, bf16_t* __restrict__ Ob) {
  __shared__ __align__(16) bf16_t Kls[64 * 128];   // [kv][dh], 16B-chunk swizzle by row&7
  __shared__ __align__(16) bf16_t Vls[128 * 64];   // [dh][kv], swizzle by row&7
  __shared__ __align__(16) bf16_t Pls[128 * 72];   // [q][kv], +8 pad

  const int tid = threadIdx.x, wave = tid >> 6, lane = tid & 63;
  const int quad = lane >> 4, l16 = lane & 15;
  const int qt = blockIdx.x, h = blockIdx.y, b = blockIdx.z;
  const int kv = h >> 2;

  // Q fragments (rope already applied): rows wave*32 + mi*16 + l16
  bf16x8 q[2][4];
#pragma unroll
  for (int mi = 0; mi < 2; ++mi) {
    const bf16_t* base =
        Qb + (size_t)(b*T_ + qt*128 + wave*32 + mi*16 + l16) * DIM_ + h*DH_;
#pragma unroll
    for (int kk = 0; kk < 4; ++kk)
      q[mi][kk] = *(const bf16x8*)(base + kk*32 + quad*8);
  }

  float m_st[2][4], l_st[2][4];
  f32x4 o_acc[2][8] = {};
#pragma unroll
  for (int mi = 0; mi < 2; ++mi)
#pragma unroll
    for (int r = 0; r < 4; ++r) { m_st[mi][r] = -3e38f; l_st[mi][r] = 0.f; }

  const int nkv = 2 * (qt + 1);
  for (int kvt = 0; kvt < nkv; ++kvt) {
    __syncthreads();  // previous iter's P/V LDS reads complete

    // stage K tile [64][128]: 16 chunks (4 rows x 256B each); swizzled
    {
      int r_in = lane >> 4, cphys = lane & 15;
#pragma unroll
      for (int c = 0; c < 4; ++c) {
        int ch = wave * 4 + c;
        int krow = ch * 4 + r_in;
        int clog = cphys ^ (krow & 7);
        gld_lds16(Kb + (size_t)(b*T_ + kvt*64 + krow) * (HKV_*DH_) + kv*DH_ + clog*8,
                  &Kls[ch*512 + lane*8]);
      }
      // stage VT tile [128][64]: 16 chunks (8 rows x 128B each); swizzled
      int r8 = lane >> 3, c8 = lane & 7;
#pragma unroll
      for (int c = 0; c < 4; ++c) {
        int ch = wave * 4 + c;
        int drow = ch * 8 + r8;
        int clog = c8 ^ (drow & 7);
        gld_lds16(VT + ((size_t)(b*HKV_ + kv) * DH_ + drow) * T_ + kvt*64 + clog*8,
                  &Vls[ch*512 + lane*8]);
      }
    }
    __syncthreads();

    // S = Q K^T (per wave: rows wave*32..+32, cols 0..64)
    f32x4 s[2][4] = {};
#pragma unroll
    for (int kk = 0; kk < 4; ++kk) {
      bf16x8 kf[4];
#pragma unroll
      for (int ni = 0; ni < 4; ++ni) {
        int krow = ni*16 + l16;
        int cphys = (kk*4 + quad) ^ (krow & 7);
        kf[ni] = *(const bf16x8*)&Kls[krow*128 + cphys*8];
      }
#pragma unroll
      for (int mi = 0; mi < 2; ++mi)
#pragma unroll
        for (int ni = 0; ni < 4; ++ni)
          s[mi][ni] = mfma16(q[mi][kk], kf[ni], s[mi][ni]);
    }

    // scale + causal mask + online softmax
    const float sc = 0.08838834764831845f;  // 1/sqrt(128)
    const bool need_mask = (kvt >= 2*qt);
#pragma unroll
    for (int mi = 0; mi < 2; ++mi) {
      float al[4];
#pragma unroll
      for (int r = 0; r < 4; ++r) {
        int rpos = qt*128 + wave*32 + mi*16 + quad*4 + r;
        float mx = -3e38f;
#pragma unroll
        for (int ni = 0; ni < 4; ++ni) {
          float v = s[mi][ni][r] * sc;
          if (need_mask) {
            int cpos = kvt*64 + ni*16 + l16;
            if (cpos > rpos) v = -3e38f;
          }
          s[mi][ni][r] = v;
          mx = fmaxf(mx, v);
        }
#pragma unroll
        for (int off = 1; off < 16; off <<= 1)
          mx = fmaxf(mx, __shfl_xor(mx, off, 64));
        float mnew = fmaxf(m_st[mi][r], mx);
        float alpha = __expf(m_st[mi][r] - mnew);
        m_st[mi][r] = mnew;
        float rs = 0.f;
#pragma unroll
        for (int ni = 0; ni < 4; ++ni) {
          float p = __expf(s[mi][ni][r] - mnew);
          s[mi][ni][r] = p;
          rs += p;
        }
#pragma unroll
        for (int off = 1; off < 16; off <<= 1)
          rs += __shfl_xor(rs, off, 64);
        l_st[mi][r] = l_st[mi][r] * alpha + rs;
        al[r] = alpha;
      }
#pragma unroll
      for (int ni = 0; ni < 8; ++ni)
#pragma unroll
        for (int r = 0; r < 4; ++r) o_acc[mi][ni][r] *= al[r];
      // P (C-layout) -> LDS row-major [128][72] bf16
#pragma unroll
      for (int ni = 0; ni < 4; ++ni)
#pragma unroll
        for (int r = 0; r < 4; ++r) {
          int prow = wave*32 + mi*16 + quad*4 + r;
          Pls[prow*72 + ni*16 + l16] = (bf16_t)s[mi][ni][r];
        }
    }
    __syncthreads();

    // O += P V : A = P[128][64], B^T = VT[128][64]
#pragma unroll
    for (int kk = 0; kk < 2; ++kk) {
      bf16x8 pf[2], vf[8];
#pragma unroll
      for (int mi = 0; mi < 2; ++mi) {
        int prow = wave*32 + mi*16 + l16;
        pf[mi] = *(const bf16x8*)&Pls[prow*72 + kk*32 + quad*8];
      }
#pragma unroll
      for (int ni = 0; ni < 8; ++ni) {
        int drow = ni*16 + l16;
        int cphys = (kk*4 + quad) ^ (drow & 7);
        vf[ni] = *(const bf16x8*)&Vls[drow*64 + cphys*8];
      }
#pragma unroll
      for (int mi = 0; mi < 2; ++mi)
#pragma unroll
        for (int ni = 0; ni < 8; ++ni)
          o_acc[mi][ni] = mfma16(pf[mi], vf[ni], o_acc[mi][ni]);
    }
  }

  // epilogue: normalize and store bf16
#pragma unroll
  for (int mi = 0; mi < 2; ++mi) {
    float inv[4];
#pragma unroll
    for (int r = 0; r < 4; ++r) inv[r] = 1.f / l_st[mi][r];
#pragma unroll
    for (int ni = 0; ni < 8; ++ni)
#pragma unroll
      for (int r = 0; r < 4; ++r) {
        size_t row = (size_t)(b*T_ + qt*128 + wave*32 + mi*16 + quad*4 + r);
        int col = h*DH_ + ni*16 + l16;
        Ob[row * DIM_ + col] = (bf16_t)(o_acc[mi][ni][r] * inv[r]);
      }
  }
}

// ---------------------------------------------------------------------------
// launch
// ---------------------------------------------------------------------------
extern "C" void kernel_launch(void* const* d_in, const int* in_sizes, int n_in,
                              void* d_out, int out_size, void* d_ws, size_t ws_size,
                              hipStream_t stream) {
  const float* X  = (const float*)d_in[0];
  const float* Wq = (const float*)d_in[1];
  const float* Wk = (const float*)d_in[2];
  const float* Wv = (const float*)d_in[3];
  const float* Wo = (const float*)d_in[4];
  float* out = (float*)d_out;

  // workspace layout (bytes); total ~176.2 MB
  char* ws = (char*)d_ws;
  const size_t SZ_X  = (size_t)MROWS * DIM_ * 2;   // 33.55 MB
  const size_t SZ_WQ = (size_t)DIM_ * DIM_ * 2;    // 33.55 MB
  const size_t SZ_WK = (size_t)DIM_ * 1024 * 2;    // 8.39 MB
  bf16_t* Xb  = (bf16_t*)(ws);                       // X bf16; reused as Ob
  bf16_t* WqT = (bf16_t*)(ws + SZ_X);
  bf16_t* WkT = (bf16_t*)(ws + SZ_X + SZ_WQ);
  bf16_t* WvT = (bf16_t*)(ws + SZ_X + SZ_WQ + SZ_WK);
  bf16_t* WoT = (bf16_t*)(ws + SZ_X + SZ_WQ + 2*SZ_WK);
  bf16_t* Qb  = (bf16_t*)(ws + SZ_X + 2*SZ_WQ + 2*SZ_WK);
  bf16_t* Kb  = (bf16_t*)(ws + 2*SZ_X + 2*SZ_WQ + 2*SZ_WK);
  bf16_t* Vb  = (bf16_t*)(ws + 2*SZ_X + 2*SZ_WQ + 3*SZ_WK);
  bf16_t* VT  = (bf16_t*)(ws + 2*SZ_X + 2*SZ_WQ + 4*SZ_WK);
  bf16_t* Ob  = Xb;  // X dead after QKV GEMMs

  // 1) casts / transposes
  {
    int n4 = MROWS * DIM_ / 4;
    cast_f32_bf16<<<(n4 + 255)/256, 256, 0, stream>>>(X, Xb, n4);
  }
  transpose_cast<<<dim3(DIM_/32, DIM_/32), dim3(32,8), 0, stream>>>(Wq, WqT, DIM_, DIM_);
  transpose_cast<<<dim3(1024/32, DIM_/32), dim3(32,8), 0, stream>>>(Wk, WkT, DIM_, 1024);
  transpose_cast<<<dim3(1024/32, DIM_/32), dim3(32,8), 0, stream>>>(Wv, WvT, DIM_, 1024);
  transpose_cast<<<dim3(DIM_/32, DIM_/32), dim3(32,8), 0, stream>>>(Wo, WoT, DIM_, DIM_);

  // 2) QKV projections
  gemm_bt<0><<<dim3(DIM_/128, MROWS/128), 256, 0, stream>>>(Xb, WqT, Qb, MROWS, DIM_, DIM_);
  gemm_bt<0><<<dim3(1024/128, MROWS/128), 256, 0, stream>>>(Xb, WkT, Kb, MROWS, 1024, DIM_);
  gemm_bt<0><<<dim3(1024/128, MROWS/128), 256, 0, stream>>>(Xb, WvT, Vb, MROWS, 1024, DIM_);

  // 3) RoPE (in place)
  {
    int totq = B_ * T_ * H_ * 64;
    rope_kernel<<<(totq + 255)/256, 256, 0, stream>>>(Qb, H_, totq);
    int totk = B_ * T_ * HKV_ * 64;
    rope_kernel<<<(totk + 255)/256, 256, 0, stream>>>(Kb, HKV_, totk);
  }

  // 4) V transpose
  v_transpose<<<dim3(T_/32, DH_/32, B_*HKV_), dim3(32,8), 0, stream>>>(Vb, VT);

  // 5) flash attention
  flash_attn<<<dim3(T_/128, H_, B_), 256, 0, stream>>>(Qb, Kb, VT, Ob);

  // 6) output projection -> fp32 d_out
  gemm_bt<1><<<dim3(DIM_/128, MROWS/128), 256, 0, stream>>>(Ob, WoT, out, MROWS, DIM_, DIM_);
}